// Round 6
// baseline (401.352 us; speedup 1.0000x reference)
//
#include <hip/hip_runtime.h>
#include <hip/hip_bf16.h>

// Causal flash attention fwd. B=2,H=16,S=2048,D=128, fp32 io, bf16 MFMA.
// R6: R3 loop structure (BM=64, single-buffer LDS, reg prefetch) +
// permuted-K rows (bpermutes deleted), launch_bounds(256,4) -> 4 blocks/CU,
// exactly balanced qt->slot map (every CU sums 66 iterations).
constexpr int Bb = 2, Hh = 16, Ss = 2048, Dd = 128;
constexpr int BM = 64, BN = 64;
constexpr int NQT = Ss / BM;                    // 32
constexpr float SCALE = 0.088388347648318447f * 1.4426950408889634f; // /sqrt(d)*log2e

constexpr int KSTRIDE = 272;                    // bytes per K row (64 rows)
constexpr int VSTRIDE = 144;                    // bytes per Vt row (128 rows)

typedef __attribute__((ext_vector_type(8))) short bf16x8;
typedef __attribute__((ext_vector_type(4))) float f32x4;
typedef __attribute__((ext_vector_type(4))) int int4v;

__device__ __forceinline__ unsigned bfbits(float f) {
  union { float f; unsigned u; } v; v.f = f;
  return v.u + 0x7FFFu + ((v.u >> 16) & 1u);    // RNE; bf16 = bits[31:16]
}
__device__ __forceinline__ unsigned pkbf(float lo, float hi) {
#if __has_builtin(__builtin_amdgcn_cvt_pk_bf16_f32)
  typedef __attribute__((ext_vector_type(2))) __bf16 bf16x2;
  bf16x2 r = __builtin_amdgcn_cvt_pk_bf16_f32(lo, hi);
  return __builtin_bit_cast(unsigned, r);
#else
  return __builtin_amdgcn_perm(bfbits(hi), bfbits(lo), 0x07060302u);
#endif
}
__device__ __forceinline__ float exp2fast(float x) {
#if __has_builtin(__builtin_amdgcn_exp2f)
  return __builtin_amdgcn_exp2f(x);
#else
  return exp2f(x);
#endif
}
__device__ __forceinline__ float fcomp(float4 f, int j) {   // j unroll-constant
  return j == 0 ? f.x : (j == 1 ? f.y : (j == 2 ? f.z : f.w));
}
// Store key k at LDS row perm(k) so S^T C-layout == PV A-fragment layout.
__device__ __forceinline__ int permrow(int key) {
  return ((key >> 5) & 1) * 16 + ((key >> 2) & 1) * 32 +
         ((key >> 3) & 3) * 4 + (key & 3);
}

__global__ __launch_bounds__(256, 4)
void fa_fwd_kernel(const float* __restrict__ q, const float* __restrict__ k,
                   const float* __restrict__ v, float* __restrict__ out) {
  __shared__ __align__(16) char Klds[BN * KSTRIDE];   // 17408 B, K[row'][d]
  __shared__ __align__(16) char Vlds[Dd * VSTRIDE];   // 18432 B, Vt[d][key]

  const int tid = threadIdx.x;
  const int wave = tid >> 6, lane = tid & 63, quad = lane >> 4, l16 = lane & 15;
  const int bid = blockIdx.x;
  const int bh = bid & 31;
  // balanced map: CU holding slots {s, s+8, s+16, s+24} sums qt -> 62 (66 iters)
  const int s = bid >> 5;
  const int qt = (s < 8) ? (31 - s) : (s < 16) ? (s - 8)
               : (s < 24) ? (39 - s) : (s - 16);

  const float* qb = q + (size_t)bh * Ss * Dd;
  const float* kb = k + (size_t)bh * Ss * Dd;
  const float* vb = v + (size_t)bh * Ss * Dd;

  // ---- Q fragments (scale*log2e folded). qrow = wave*16+l16, d = 32ks+8quad+j
  bf16x8 qf[4];
  {
    const float* qr = qb + (size_t)(qt * BM + wave * 16 + l16) * Dd + quad * 8;
    #pragma unroll
    for (int ks = 0; ks < 4; ++ks) {
      float4 a = *(const float4*)(qr + ks * 32);
      float4 b = *(const float4*)(qr + ks * 32 + 4);
      int4v t = { (int)pkbf(a.x*SCALE, a.y*SCALE), (int)pkbf(a.z*SCALE, a.w*SCALE),
                  (int)pkbf(b.x*SCALE, b.y*SCALE), (int)pkbf(b.z*SCALE, b.w*SCALE) };
      qf[ks] = __builtin_bit_cast(bf16x8, t);
    }
  }

  // ---- staging geometry
  const int krow0 = tid >> 4;            // K: rows krow0+16i (i<4), d-block kblk
  const int kblk  = tid & 15;
  const int vdq = tid >> 3;              // V: d rows 4*vdq..+3, keys vkg*8..+7
  const int vkg = tid & 7;

  float4 ka[4], kc[4];                   // K prefetch (8 fp32 per row)
  float4 vr[8];                          // V prefetch (8 key-rows x 4 d)

  auto load_tiles = [&](int kt) {
    const float* Kg = kb + (size_t)(kt * BN) * Dd + kblk * 8;
    #pragma unroll
    for (int i = 0; i < 4; ++i) {
      ka[i] = *(const float4*)(Kg + (size_t)(krow0 + 16 * i) * Dd);
      kc[i] = *(const float4*)(Kg + (size_t)(krow0 + 16 * i) * Dd + 4);
    }
    const float* Vg = vb + (size_t)(kt * BN + vkg * 8) * Dd + vdq * 4;
    #pragma unroll
    for (int r = 0; r < 8; ++r)
      vr[r] = *(const float4*)(Vg + (size_t)r * Dd);
  };

  auto stage_tiles = [&]() {
    #pragma unroll
    for (int i = 0; i < 4; ++i) {
      int row = permrow(krow0 + 16 * i);
      int4v t = { (int)pkbf(ka[i].x, ka[i].y), (int)pkbf(ka[i].z, ka[i].w),
                  (int)pkbf(kc[i].x, kc[i].y), (int)pkbf(kc[i].z, kc[i].w) };
      *(int4v*)(Klds + row * KSTRIDE + kblk * 16) = t;
    }
    #pragma unroll
    for (int j = 0; j < 4; ++j) {
      int d = vdq * 4 + j;
      int4v t = { (int)pkbf(fcomp(vr[0], j), fcomp(vr[1], j)),
                  (int)pkbf(fcomp(vr[2], j), fcomp(vr[3], j)),
                  (int)pkbf(fcomp(vr[4], j), fcomp(vr[5], j)),
                  (int)pkbf(fcomp(vr[6], j), fcomp(vr[7], j)) };
      *(int4v*)(Vlds + d * VSTRIDE + vkg * 16) = t;
    }
  };

  f32x4 o[8];
  #pragma unroll
  for (int i = 0; i < 8; ++i) o[i] = (f32x4)(0.0f);
  float mrow = -3.0e38f, lrow = 0.0f;    // per-lane: qrow = wave*16 + l16

  load_tiles(0);
  stage_tiles();

  const char* Krd = Klds + l16 * KSTRIDE + quad * 16;
  const char* Vrd = Vlds + l16 * VSTRIDE + quad * 16;

  for (int kt = 0; kt <= qt; ++kt) {
    __syncthreads();                     // tile kt visible
    const bool more = kt < qt;
    if (more) load_tiles(kt + 1);        // prefetch next tile into regs

    // ---- S^T: acc[nt][r] = S[q=l16][row' = nt*16+quad*4+r]  (log2 units)
    f32x4 acc[4];
    #pragma unroll
    for (int nt = 0; nt < 4; ++nt) acc[nt] = (f32x4)(0.0f);
    #pragma unroll
    for (int ks = 0; ks < 4; ++ks) {
      #pragma unroll
      for (int nt = 0; nt < 4; ++nt) {
        bf16x8 kf = *(const bf16x8*)(Krd + nt * (16 * KSTRIDE) + ks * 64);
        acc[nt] = __builtin_amdgcn_mfma_f32_16x16x32_bf16(kf, qf[ks], acc[nt], 0, 0, 0);
      }
    }

    // ---- causal mask on diagonal tile (key remapped through permrow)
    if (kt == qt) {
      #pragma unroll
      for (int nt = 0; nt < 4; ++nt)
        #pragma unroll
        for (int r = 0; r < 4; ++r) {
          int key = 32 * (nt & 1) + 8 * quad + 4 * (nt >> 1) + r;
          if (key > wave * 16 + l16) acc[nt][r] = -1.0e30f;
        }
    }

    // ---- online softmax (base-2); reduce across the 4 lanes sharing l16
    float mx = acc[0][0];
    #pragma unroll
    for (int nt = 0; nt < 4; ++nt)
      #pragma unroll
      for (int r = 0; r < 4; ++r) mx = fmaxf(mx, acc[nt][r]);
    mx = fmaxf(mx, __shfl_xor(mx, 16, 64));
    mx = fmaxf(mx, __shfl_xor(mx, 32, 64));
    float mn = fmaxf(mrow, mx);
    float alpha = 1.0f;
    if (__any(mx > mrow)) {
      alpha = exp2fast(mrow - mn);
      #pragma unroll
      for (int r = 0; r < 4; ++r) {
        int src = (lane & 48) | (quad * 4 + r);
        float ar = __shfl(alpha, src, 64);
        #pragma unroll
        for (int dt = 0; dt < 8; ++dt) o[dt][r] *= ar;
      }
    }
    mrow = mn;
    float rs = 0.f;
    #pragma unroll
    for (int nt = 0; nt < 4; ++nt)
      #pragma unroll
      for (int r = 0; r < 4; ++r) {
        float p = exp2fast(acc[nt][r] - mn);
        acc[nt][r] = p; rs += p;
      }
    rs += __shfl_xor(rs, 16, 64);
    rs += __shfl_xor(rs, 32, 64);
    lrow = lrow * alpha + rs;

    // ---- P A-fragments: pure register pack (permuted rows align C->A)
    bf16x8 pf[2];
    #pragma unroll
    for (int ks2 = 0; ks2 < 2; ++ks2) {
      int4v t = { (int)pkbf(acc[ks2][0],     acc[ks2][1]),
                  (int)pkbf(acc[ks2][2],     acc[ks2][3]),
                  (int)pkbf(acc[ks2 + 2][0], acc[ks2 + 2][1]),
                  (int)pkbf(acc[ks2 + 2][2], acc[ks2 + 2][3]) };
      pf[ks2] = __builtin_bit_cast(bf16x8, t);
    }

    // ---- O += P V
    #pragma unroll
    for (int ks2 = 0; ks2 < 2; ++ks2) {
      #pragma unroll
      for (int dt = 0; dt < 8; ++dt) {
        bf16x8 vf = *(const bf16x8*)(Vrd + dt * (16 * VSTRIDE) + ks2 * 64);
        o[dt] = __builtin_amdgcn_mfma_f32_16x16x32_bf16(pf[ks2], vf, o[dt], 0, 0, 0);
      }
    }

    if (more) { __syncthreads(); stage_tiles(); }   // prefetch resolves here
  }

  // ---- epilogue: O / l
  float linv[4];
  #pragma unroll
  for (int r = 0; r < 4; ++r) {
    int src = (lane & 48) | (quad * 4 + r);
    linv[r] = 1.0f / __shfl(lrow, src, 64);
  }
  float* ob = out + ((size_t)bh * Ss + qt * BM + wave * 16) * Dd;
  #pragma unroll
  for (int dt = 0; dt < 8; ++dt)
    #pragma unroll
    for (int r = 0; r < 4; ++r)
      ob[(quad * 4 + r) * Dd + dt * 16 + l16] = o[dt][r] * linv[r];
}

extern "C" void kernel_launch(void* const* d_in, const int* in_sizes, int n_in,
                              void* d_out, int out_size, void* d_ws, size_t ws_size,
                              hipStream_t stream) {
  const float* q = (const float*)d_in[0];
  const float* k = (const float*)d_in[1];
  const float* v = (const float*)d_in[2];
  float* out = (float*)d_out;
  dim3 grid(Bb * Hh * NQT);   // 1024
  dim3 block(256);
  hipLaunchKernelGGL(fa_fwd_kernel, grid, block, 0, stream, q, k, v, out);
}